// Round 3
// baseline (249.562 us; speedup 1.0000x reference)
//
#include <hip/hip_runtime.h>
#include <hip/hip_bf16.h>

// Problem constants (fixed by the reference setup)
#define BB 8
#define SS 4096
#define DD 1024
#define HH 16
#define HD 64
#define NR 32
#define NROWS (BB * SS * HH)       // 524288 head-vectors of length 64
#define NTILES (NROWS / 16)        // 32768 m-tiles of 16 rows
#define TPW 4                      // tiles per wave

using frag_ab = __attribute__((ext_vector_type(8))) short;  // 8 bf16 (4 VGPRs)
using frag_cd = __attribute__((ext_vector_type(4))) float;  // 4 fp32

// fp32 -> bf16 round-to-nearest-even (bit pattern in ushort)
static __device__ __forceinline__ unsigned short f2bf(float f) {
    union { float f; unsigned u; } v; v.f = f;
    unsigned r = v.u + 0x7fffu + ((v.u >> 16) & 1u);
    return (unsigned short)(r >> 16);
}

// ---------------------------------------------------------------------------
// Kernel A: build C = M0*M1*...*M31 * r_matrix via reverse-order row ops,
// then pack it as bf16 into MFMA B-fragment layout (16x16x32), with the
// column permutation: packed col pos p<32 -> orig col 2p (even ycols),
// p>=32 -> orig col 2(p-32)+1 (odd ycols). This makes each RoPE pair
// (y[2c], y[2c+1]) land in the SAME lane of acc[nt] / acc[nt+2].
// ---------------------------------------------------------------------------
__global__ __launch_bounds__(256) void build_C_kernel(
    const float* __restrict__ thetas,
    const float* __restrict__ r_pairs,
    const float* __restrict__ theta_scale,
    const float* __restrict__ r_matrix,
    unsigned short* __restrict__ Cpk)     // 4096 bf16 = 8 KB
{
    __shared__ float W[64 * 68];     // 64x64, row stride 68
    __shared__ int   ii[NR], jj[NR];
    __shared__ float cc[NR], ss[NR];

    const int t = threadIdx.x;

#pragma unroll
    for (int it = 0; it < 16; ++it) {
        int idx = t + 256 * it;                  // 0..4095
        W[(idx >> 6) * 68 + (idx & 63)] = r_matrix[idx];
    }
    if (t < NR) {
        ii[t] = (int)r_pairs[2 * t];
        jj[t] = (int)r_pairs[2 * t + 1];
        float th = thetas[t] * theta_scale[0];
        cc[t] = cosf(th);
        ss[t] = sinf(th);
    }
    __syncthreads();

    // W <- Mk * W for k = 31..0 (row ops; thread t owns column t)
    if (t < 64) {
        for (int k = NR - 1; k >= 0; --k) {
            int i = ii[k], j = jj[k];
            float c = cc[k], s = ss[k];
            float xi = W[i * 68 + t];
            float xj = W[j * 68 + t];
            if (i == j) {
                W[i * 68 + t] = c * xi;
            } else {
                W[i * 68 + t] = c * xi - s * xj;
                W[j * 68 + t] = s * xi + c * xj;
            }
        }
    }
    __syncthreads();

    // Pack into B-frag order: frag f = kt*4 + nt; within frag: lane, j.
    // B[k][npos]: npos = nt*16 + (lane&15), k = kt*32 + (lane>>4)*8 + j.
#pragma unroll
    for (int it = 0; it < 16; ++it) {
        int idx  = t * 16 + it;          // 0..4095
        int f    = idx >> 9;
        int rem  = idx & 511;
        int lane = rem >> 3;
        int j    = rem & 7;
        int kt   = f >> 2, nt = f & 3;
        int q    = lane >> 4, nl = lane & 15;
        int k    = kt * 32 + q * 8 + j;
        int npos = nt * 16 + nl;
        int oc   = (npos < 32) ? (npos << 1) : (((npos - 32) << 1) | 1);
        Cpk[idx] = f2bf(W[k * 68 + oc]);
    }
}

// ---------------------------------------------------------------------------
// Kernel B: MFMA matvec (16 rows/tile) fused with RoPE. No LDS, no barriers.
// Each wave: 8 B-frags in registers (loaded once), then TPW tiles:
//   A direct from global in A-frag layout -> 8 MFMAs -> in-lane RoPE pairing
//   (even/odd split baked into C's column permutation) -> scalar stores
//   (each store instr = 4 rows x 64B contiguous segments).
// ---------------------------------------------------------------------------
__global__ __launch_bounds__(256, 4) void rope_mfma_kernel(
    const float* __restrict__ x,
    const unsigned short* __restrict__ Cpk,
    const float* __restrict__ inv_freq,
    float* __restrict__ out)
{
    const int t  = threadIdx.x;
    const int l  = t & 63;
    const int q  = l >> 4;           // quad 0..3
    const int nl = l & 15;
    const int w  = (blockIdx.x * 256 + t) >> 6;   // global wave id
    const int tile0 = w * TPW;

    // B fragments (8 x 16B = coalesced uint4 loads, L2-resident)
    frag_ab B[8];
    {
        const uint4* cp = (const uint4*)Cpk;
#pragma unroll
        for (int f = 0; f < 8; ++f) {
            union { uint4 u; frag_ab s; } cvt;
            cvt.u = cp[f * 64 + l];
            B[f] = cvt.s;
        }
    }
    const float invf0 = inv_freq[nl];
    const float invf1 = inv_freq[16 + nl];

    // A prefetch registers: 8 k-values for kt=0 (a[0],a[1]) and kt=1 (a[2],a[3])
    float4 a[4];
    {
        const float* xr = x + ((size_t)tile0 * 16 + nl) * 64 + q * 8;
        a[0] = *(const float4*)(xr);
        a[1] = *(const float4*)(xr + 4);
        a[2] = *(const float4*)(xr + 32);
        a[3] = *(const float4*)(xr + 36);
    }

#pragma unroll
    for (int tt = 0; tt < TPW; ++tt) {
        const int tl = tile0 + tt;

        // software prefetch of next tile's A
        float4 an[4];
        if (tt + 1 < TPW) {
            const float* xr = x + ((size_t)(tl + 1) * 16 + nl) * 64 + q * 8;
            an[0] = *(const float4*)(xr);
            an[1] = *(const float4*)(xr + 4);
            an[2] = *(const float4*)(xr + 32);
            an[3] = *(const float4*)(xr + 36);
        }

        // convert current A to bf16 frags
        frag_ab a0, a1;
        {
            const float* af = (const float*)&a[0];
#pragma unroll
            for (int j = 0; j < 8; ++j) a0[j] = (short)f2bf(af[j]);
#pragma unroll
            for (int j = 0; j < 8; ++j) a1[j] = (short)f2bf(af[8 + j]);
        }

        frag_cd acc0 = {0.f, 0.f, 0.f, 0.f};
        frag_cd acc1 = acc0, acc2 = acc0, acc3 = acc0;
        acc0 = __builtin_amdgcn_mfma_f32_16x16x32_bf16(a0, B[0], acc0, 0, 0, 0);
        acc1 = __builtin_amdgcn_mfma_f32_16x16x32_bf16(a0, B[1], acc1, 0, 0, 0);
        acc2 = __builtin_amdgcn_mfma_f32_16x16x32_bf16(a0, B[2], acc2, 0, 0, 0);
        acc3 = __builtin_amdgcn_mfma_f32_16x16x32_bf16(a0, B[3], acc3, 0, 0, 0);
        acc0 = __builtin_amdgcn_mfma_f32_16x16x32_bf16(a1, B[4], acc0, 0, 0, 0);
        acc1 = __builtin_amdgcn_mfma_f32_16x16x32_bf16(a1, B[5], acc1, 0, 0, 0);
        acc2 = __builtin_amdgcn_mfma_f32_16x16x32_bf16(a1, B[6], acc2, 0, 0, 0);
        acc3 = __builtin_amdgcn_mfma_f32_16x16x32_bf16(a1, B[7], acc3, 0, 0, 0);

        // RoPE epilogue: all 16 rows of this tile share position tl % S.
        // Lane holds y_even[c] in acc0/acc1 (c = nt*16+nl) and y_odd[c] in
        // acc2/acc3 (same lane) thanks to the packed column permutation.
        const float pos = (float)(tl & (SS - 1));
        float sn0, cs0, sn1, cs1;
        __sincosf(pos * invf0, &sn0, &cs0);
        __sincosf(pos * invf1, &sn1, &cs1);

        float* ob = out + ((size_t)tl * 16 + q * 4) * 64;   // D rows = q*4 + r
#pragma unroll
        for (int r = 0; r < 4; ++r) {
            float* orow = ob + (size_t)r * 64;
            orow[nl]      = acc0[r] * cs0 - acc2[r] * sn0;
            orow[32 + nl] = acc0[r] * sn0 + acc2[r] * cs0;
            orow[16 + nl] = acc1[r] * cs1 - acc3[r] * sn1;
            orow[48 + nl] = acc1[r] * sn1 + acc3[r] * cs1;
        }

        if (tt + 1 < TPW) {
            a[0] = an[0]; a[1] = an[1]; a[2] = an[2]; a[3] = an[3];
        }
    }
}

// ---------------------------------------------------------------------------
extern "C" void kernel_launch(void* const* d_in, const int* in_sizes, int n_in,
                              void* d_out, int out_size, void* d_ws, size_t ws_size,
                              hipStream_t stream)
{
    const float* x           = (const float*)d_in[0];
    const float* thetas      = (const float*)d_in[1];
    const float* r_pairs     = (const float*)d_in[2];
    const float* theta_scale = (const float*)d_in[3];
    // d_in[4] = n_rots_scale (unused by the reference)
    const float* r_matrix    = (const float*)d_in[5];
    const float* inv_freq    = (const float*)d_in[6];
    float* out = (float*)d_out;
    unsigned short* Cpk = (unsigned short*)d_ws;   // 8 KB packed bf16 B-frags

    build_C_kernel<<<1, 256, 0, stream>>>(thetas, r_pairs, theta_scale, r_matrix, Cpk);

    const int nblocks = NTILES / (TPW * 4);        // 32768 / 16 = 2048
    rope_mfma_kernel<<<nblocks, 256, 0, stream>>>(x, Cpk, inv_freq, out);
}